// Round 6
// baseline (386.182 us; speedup 1.0000x reference)
//
#include <hip/hip_runtime.h>

#define NQ     2048
#define NB     8
#define ROWS   8                     // i-rows per block
#define TPB    256
#define HALVES 2                     // j-tile = 1024 columns per block
#define NBLK   (NB * (NQ / ROWS) * HALVES)   // 4096 blocks

typedef float floatx4 __attribute__((ext_vector_type(4)));

__global__ __launch_bounds__(TPB, 4) void idla_main(
        const float* __restrict__ preds,
        const float* __restrict__ targets,
        const float* __restrict__ adj,
        double* __restrict__ ws,
        float* __restrict__ out) {
    __shared__ float red_sq[TPB / 64], red_ad[TPB / 64];

    const int rem  = blockIdx.x & 511;          // 512 blocks per batch
    const int b    = blockIdx.x >> 9;
    const int i0   = (rem >> 1) * ROWS;
    const int half = rem & 1;
    const int tid  = threadIdx.x;

    const float* pb   = preds   + (size_t)b * NQ * 3;
    const float* tb   = targets + (size_t)b * NQ * 3;
    const float* adjb = adj     + (size_t)b * NQ * NQ;

    const int j0 = half * (NQ / 2) + tid * 4;   // this thread's 4 j-columns

    // ---- 1) j-coord vector loads FIRST (vmcnt is in-order: these must not
    //         queue behind the adj stream) ----
    const float* p = pb + (size_t)j0 * 3;
    const float* t = tb + (size_t)j0 * 3;
    floatx4 pa = *(const floatx4*)(p);
    floatx4 pc = *(const floatx4*)(p + 4);
    floatx4 pe = *(const floatx4*)(p + 8);
    floatx4 ta = *(const floatx4*)(t);
    floatx4 tc = *(const floatx4*)(t + 4);
    floatx4 te = *(const floatx4*)(t + 8);

    // ---- 2) all ROWS adj loads issued back-to-back: 8 KB/wave in flight ----
    const float* abase = adjb + (size_t)i0 * NQ + j0;
    floatx4 a4[ROWS];
    #pragma unroll
    for (int r = 0; r < ROWS; r++)
        a4[r] = __builtin_nontemporal_load((const floatx4*)(abase + (size_t)r * NQ));

    // Forbid the scheduler from sinking the loads into the consume loop.
    __builtin_amdgcn_sched_barrier(0);

    // ---- 3) i-coords: block-uniform -> scalar loads (8 rows, consecutive) ----
    float ipx[ROWS], ipy[ROWS], ipz[ROWS], itx[ROWS], ity[ROWS], itz[ROWS];
    #pragma unroll
    for (int ii = 0; ii < ROWS; ii++) {
        const int i = i0 + ii;
        ipx[ii] = pb[i * 3 + 0]; ipy[ii] = pb[i * 3 + 1]; ipz[ii] = pb[i * 3 + 2];
        itx[ii] = tb[i * 3 + 0]; ity[ii] = tb[i * 3 + 1]; itz[ii] = tb[i * 3 + 2];
    }

    // Unpack j-coords (AoS floatx4 triplets -> SoA registers)
    const float jpx[4] = {pa.x, pa.w, pc.z, pe.y};
    const float jpy[4] = {pa.y, pc.x, pc.w, pe.z};
    const float jpz[4] = {pa.z, pc.y, pe.x, pe.w};
    const float jtx[4] = {ta.x, ta.w, tc.z, te.y};
    const float jty[4] = {ta.y, tc.x, tc.w, te.z};
    const float jtz[4] = {ta.z, tc.y, te.x, te.w};

    float acc_sq = 0.0f;
    float acc_ad = 0.0f;

    // ---- 4) consume rows in issue order (vmcnt 7,6,...,0) ----
    #pragma unroll
    for (int r = 0; r < ROWS; r++) {
        const float pix = ipx[r], piy = ipy[r], piz = ipz[r];
        const float tix = itx[r], tiy = ity[r], tiz = itz[r];
        const float av[4] = {a4[r].x, a4[r].y, a4[r].z, a4[r].w};
        #pragma unroll
        for (int jj = 0; jj < 4; jj++) {
            float dx = pix - jpx[jj];
            float dy = piy - jpy[jj];
            float dz = piz - jpz[jj];
            float sa = fmaf(dx, dx, fmaf(dy, dy, dz * dz));   // |p_i-p_j|^2
            float ex = tix - jtx[jj];
            float ey = tiy - jty[jj];
            float ez = tiz - jtz[jj];
            float sb = fmaf(ex, ex, fmaf(ey, ey, ez * ez));   // |t_i-t_j|^2
            // (sqrt(sa)-sqrt(sb))^2 = sa + sb - 2*sqrt(sa*sb)  [one sqrt]
            float s  = __builtin_amdgcn_sqrtf(sa * sb);
            float tt = fmaf(-2.0f, s, sa + sb);
            acc_sq = fmaf(av[jj], tt, acc_sq);
            acc_ad += av[jj];
        }
    }

    // ---- wave64 shuffle reduction, then cross-wave via tiny LDS ----
    #pragma unroll
    for (int off = 32; off > 0; off >>= 1) {
        acc_sq += __shfl_down(acc_sq, off, 64);
        acc_ad += __shfl_down(acc_ad, off, 64);
    }
    const int wave = tid >> 6;
    if ((tid & 63) == 0) { red_sq[wave] = acc_sq; red_ad[wave] = acc_ad; }
    __syncthreads();
    if (tid == 0) {
        float s_sq = 0.0f, s_ad = 0.0f;
        #pragma unroll
        for (int w = 0; w < TPB / 64; w++) { s_sq += red_sq[w]; s_ad += red_ad[w]; }
        atomicAdd(&ws[0], (double)s_sq);
        atomicAdd(&ws[1], (double)s_ad);
        __threadfence();
        unsigned* cnt = (unsigned*)(ws + 2);
        unsigned done = atomicAdd(cnt, 1u);
        if (done == NBLK - 1) {
            double sq = atomicAdd(&ws[0], 0.0);
            double ad = atomicAdd(&ws[1], 0.0);
            out[0] = (float)(sq / ad);
        }
    }
}

extern "C" void kernel_launch(void* const* d_in, const int* in_sizes, int n_in,
                              void* d_out, int out_size, void* d_ws, size_t ws_size,
                              hipStream_t stream) {
    const float* preds   = (const float*)d_in[0];
    const float* targets = (const float*)d_in[1];
    const float* adj     = (const float*)d_in[2];
    double* ws  = (double*)d_ws;
    float*  out = (float*)d_out;

    // ws[0]=sum_sq, ws[1]=sum_adj (doubles), ws+2: unsigned done-counter
    (void)hipMemsetAsync(ws, 0, 24, stream);
    hipLaunchKernelGGL(idla_main, dim3(NBLK), dim3(TPB), 0, stream,
                       preds, targets, adj, ws, out);
}